// Round 5
// baseline (381.376 us; speedup 1.0000x reference)
//
#include <hip/hip_runtime.h>
#include <math.h>

// Problem constants
constexpr int BQ   = 2048;
constexpr int D    = 256;
constexpr int NMEM = 100000;
constexpr int TOPK = 16;
constexpr int NCLS = 1000;
constexpr float TAU = 0.2f;
constexpr float LOGIT_SCALE = 20.0f;

// fp8(e4m3) GEMM (K=256) for candidate SELECTION only, now via the 2x-rate
// mfma_scale_f32_32x32x64_f8f6f4 (scales pinned to 1.0 = e8m0 0x7f).
// Correctness note: any internal k-permutation of the 32-byte lane fragment
// cancels, because A and B are fed through IDENTICAL granule layouts and a
// dot product is k-permutation-invariant. Row/col = lane&31 matches the
// HW-verified 32x32 C/D layout family.
// fp8 sim noise sigma ~0.038; gap s16-s64 = 0.34 = 6.3 sigma -> approx
// top-64 superset contains the true top-16; knn_final re-ranks exactly.
constexpr int KTOT = 256;        // k-elements (= bytes in fp8)
constexpr int BK   = 64;         // k per k-step (64 B/row, 8 KB tile)
constexpr int TM   = 128;
constexpr int TN   = 128;
constexpr int CTILES = 13;
constexpr int CHUNK  = TN * CTILES;               // 1664
constexpr int NCH    = 64;                        // 64*1664 = 106496 >= 100000
constexpr int RBLK   = BQ / TM;                   // 16
constexpr int NBLK   = RBLK * NCH;                // 1024 = 4 blocks/CU exact
constexpr int TOTAL_IT = CTILES * (KTOT / BK);    // 52
constexpr float XSCALE = 16.0f;
constexpr float INV_XS = 0.0625f;
constexpr float THR    = 3.0f;   // candidate floor (mean ~136/row above it)
constexpr float THRS   = 48.0f;  // THR * XSCALE (raw acc scale)
constexpr int CAP    = 512;      // per-row candidate cap
constexpr int MSEL   = 64;       // refinement superset target
constexpr int SELCAP = 96;
constexpr float NEG  = -3.0e38f;

using i32x4  = __attribute__((ext_vector_type(4))) int;
using i32x8  = __attribute__((ext_vector_type(8))) int;
using f32x16 = __attribute__((ext_vector_type(16))) float;

// f32 -> OCP e4m3 (RNE, clamp to 448, flush subnormals — inputs pre-scaled
// so the flush region carries negligible mass).
__device__ __forceinline__ unsigned f2e4m3(float f) {
    const unsigned u = __float_as_uint(f);
    const unsigned s = (u >> 24) & 0x80u;
    const int e = (int)((u >> 23) & 0xff);
    int te = e - 120;                          // e4m3 exponent field (bias 7)
    if (te <= 0) return s;                     // flush tiny
    const unsigned m = u & 0x7fffffu;
    const unsigned r = m + 0x7ffffu + ((m >> 20) & 1u);
    unsigned keep;
    if (r & 0x800000u) { ++te; keep = 0; } else keep = (r >> 20) & 7u;
    if (te >= 16 || (te == 15 && keep == 7)) return s | 0x7eu;  // clamp 448
    return s | ((unsigned)te << 3) | keep;
}

__device__ __forceinline__ void load_lds16(const void* g, void* l) {
    __builtin_amdgcn_global_load_lds((const __attribute__((address_space(1))) void*)g,
                                     (__attribute__((address_space(3))) void*)l,
                                     16, 0, 0);
}

// ---------------------------------------------------------------------------
// Phase A: standardize + L2-normalize; emit A1 = e4m3(16*x_hat), XN = f32
// x_hat, and zero the per-row candidate counters.
// ---------------------------------------------------------------------------
__global__ __launch_bounds__(256) void knn_prep(
    const float* __restrict__ x, const float* __restrict__ mean,
    const float* __restrict__ stdv, unsigned char* __restrict__ A1,
    float* __restrict__ XN, int* __restrict__ cnt)
{
    const int row = blockIdx.x;
    const int t = threadIdx.x;                       // feature index, D==256
    float v = (x[row * D + t] - mean[t]) / stdv[t];
    float s = v * v;
    #pragma unroll
    for (int off = 32; off > 0; off >>= 1) s += __shfl_down(s, off, 64);
    __shared__ float wsum[4];
    __shared__ float nrm;
    const int lane = t & 63, wid = t >> 6;
    if (lane == 0) wsum[wid] = s;
    __syncthreads();
    if (t == 0) {
        nrm = fmaxf(sqrtf(wsum[0] + wsum[1] + wsum[2] + wsum[3]), 1e-6f);
        cnt[row] = 0;
    }
    __syncthreads();
    const float xnv = v / nrm;
    A1[(size_t)row * KTOT + t] = (unsigned char)f2e4m3(xnv * XSCALE);
    XN[(size_t)row * D + t] = xnv;
}

// ---------------------------------------------------------------------------
// Phase A2: mem_features -> B1 = e4m3(mem); 8 rows/block, float4 -> 8 bytes
// ---------------------------------------------------------------------------
__global__ __launch_bounds__(256) void knn_convb(
    const float* __restrict__ mem, unsigned char* __restrict__ B1)
{
    const int tid = threadIdx.x;
    const int rloc = tid >> 5, t = tid & 31;         // 32 threads per row
    const long n = (long)blockIdx.x * 8 + rloc;
    if (n >= NMEM) return;
    const float* src = mem + n * D + t * 8;
    const float4 v0 = *(const float4*)(src);
    const float4 v1 = *(const float4*)(src + 4);
    const float f[8] = {v0.x, v0.y, v0.z, v0.w, v1.x, v1.y, v1.z, v1.w};
    unsigned long long pk = 0;
    #pragma unroll
    for (int i = 0; i < 8; ++i)
        pk |= (unsigned long long)f2e4m3(f[i]) << (8 * i);
    *(unsigned long long*)(B1 + n * KTOT + t * 8) = pk;
}

// ---------------------------------------------------------------------------
// Phase B: double-buffered MX-fp8 MFMA GEMM (32x32x64, unit scales);
// candidates above THRS appended to a per-row global list.
//  * staging geometry byte-identical to the verified kernel (16-B granules,
//    4/row, (sl+(r>>1))&3 rotation, linear global_load_lds dest).
//  * frag reads: 8x ds_read_b128 per wave-iter (32 contiguous k-bytes/lane)
//    — replaces 16x 4-way-conflicted b64 (round-4: 1.36e7 conflict cycles).
//  * MFMA: 4x 32x32x64 per wave-iter at the 2x MX rate (floor 55 -> 24 us).
//  * occupancy: 4 blocks/CU needs VGPR+acc <= 128/wave. Tripwire: scratch.
// ---------------------------------------------------------------------------
__global__ __launch_bounds__(256, 4) void knn_gemm_topk(
    const unsigned char* __restrict__ A1, const unsigned char* __restrict__ B1,
    int* __restrict__ cnt, uint2* __restrict__ cand_buf)
{
    __shared__ alignas(16) unsigned char As[2][TM * BK];   // 8 KB each
    __shared__ alignas(16) unsigned char Bs[2][TN * BK];   // 8 KB each

    const int tid  = threadIdx.x;
    const int lane = tid & 63, wave = tid >> 6;
    const int wm = wave >> 1, wn = wave & 1;
    const int l31 = lane & 31;                             // out row/col in tile
    const int kb  = lane >> 5;                             // k-half of BK=64

    // chunk-exclusive XCD decode: id%8 == XCD (perf heuristic only)
    const int nblk = blockIdx.x;
    const int xcd = nblk & 7, bi = nblk >> 3;              // bi in [0,128)
    const int rb = bi & 15;                                // rowblk in [0,16)
    const int ch = (bi >> 4) + 8 * xcd;                    // chunk  in [0,64)
    const int row0  = rb * TM;
    const int cbase = ch * CHUNK;

    // frag byte offsets, k-loop invariant: [out-tile][granule c of the 32B]
    // lane reads 32 B = granules (row, 2*kb+c), phys seg = (L-(row>>1))&3
    int aoff[2][2], boff[2][2];
    #pragma unroll
    for (int ti = 0; ti < 2; ++ti) {
        const int ar = wm * 64 + ti * 32 + l31;
        const int br = wn * 64 + ti * 32 + l31;
        #pragma unroll
        for (int c = 0; c < 2; ++c) {
            aoff[ti][c] = ar * BK + (((2 * kb + c) - (ar >> 1)) & 3) * 16;
            boff[ti][c] = br * BK + (((2 * kb + c) - (br >> 1)) & 3) * 16;
        }
    }

    // per-thread staging geometry (16B granule s of this thread)
    const unsigned char* aSrc[2];                          // +kk per iter
    int cSub[2], bSeg[2];
    #pragma unroll
    for (int s = 0; s < 2; ++s) {
        const int ci = s * 256 + tid;
        const int r = ci >> 2, sl = ci & 3;
        aSrc[s] = A1 + (size_t)(row0 + r) * KTOT + (((sl + (r >> 1)) & 3) << 4);
        cSub[s] = r;
        bSeg[s] = ((sl + (r >> 1)) & 3) << 4;
    }
    // per-tile B base pointers (clamped; recomputed only at tile switch)
    const unsigned char* bB[2];
    auto computeBB = [&](int tile) {
        #pragma unroll
        for (int s = 0; s < 2; ++s) {
            int candi = cbase + tile * TN + cSub[s];
            if (candi >= NMEM) candi = NMEM - 1;
            bB[s] = B1 + (size_t)candi * KTOT + bSeg[s];
        }
    };

    f32x16 acc[2][2];
    #pragma unroll
    for (int i = 0; i < 2; ++i)
        #pragma unroll
        for (int j = 0; j < 2; ++j)
            #pragma unroll
            for (int r = 0; r < 16; ++r) acc[i][j][r] = 0.f;

    int t = 0, kk = 0, p = 0;
    computeBB(0);
    {   // stage k-step 0 of tile 0 into buffer 0
        #pragma unroll
        for (int s = 0; s < 2; ++s)
            load_lds16(aSrc[s], (char*)As[0] + s * 4096 + wave * 1024);
        #pragma unroll
        for (int s = 0; s < 2; ++s)
            load_lds16(bB[s], (char*)Bs[0] + s * 4096 + wave * 1024);
    }
    __syncthreads();

    for (int it = 0; it < TOTAL_IT; ++it) {
        const bool last = (kk == KTOT - BK);               // last k-step of tile
        const int tn = last ? t + 1 : t;
        const int kn = last ? 0 : kk + BK;

        // 1) frag ds_reads from buffer p (no outstanding vmem -> no stall)
        const unsigned char* Ab = As[p];
        const unsigned char* Bb = Bs[p];
        i32x8 Afr[2], Bfr[2];
        #pragma unroll
        for (int ti = 0; ti < 2; ++ti) {
            const i32x4 alo = *(const i32x4*)(Ab + aoff[ti][0]);
            const i32x4 ahi = *(const i32x4*)(Ab + aoff[ti][1]);
            Afr[ti] = __builtin_shufflevector(alo, ahi, 0, 1, 2, 3, 4, 5, 6, 7);
            const i32x4 blo = *(const i32x4*)(Bb + boff[ti][0]);
            const i32x4 bhi = *(const i32x4*)(Bb + boff[ti][1]);
            Bfr[ti] = __builtin_shufflevector(blo, bhi, 0, 1, 2, 3, 4, 5, 6, 7);
        }

        // 2) issue prefetch of next k-step into buffer p^1
        if (tn < CTILES) {
            if (last) computeBB(tn);
            #pragma unroll
            for (int s = 0; s < 2; ++s)
                load_lds16(aSrc[s] + kn, (char*)As[p ^ 1] + s * 4096 + wave * 1024);
            #pragma unroll
            for (int s = 0; s < 2; ++s)
                load_lds16(bB[s] + kn, (char*)Bs[p ^ 1] + s * 4096 + wave * 1024);
        }

        // 3) MFMA: 2x2 out-tiles of 32x32, full K=64 per instruction.
        //    fp8 fmt = 0 for both operands; scales = 1.0 (e8m0 0x7f, all bytes)
        #pragma unroll
        for (int ti = 0; ti < 2; ++ti)
            #pragma unroll
            for (int tj = 0; tj < 2; ++tj)
                acc[ti][tj] = __builtin_amdgcn_mfma_scale_f32_32x32x64_f8f6f4(
                    Afr[ti], Bfr[tj], acc[ti][tj], 0, 0,
                    0, 0x7f7f7f7f, 0, 0x7f7f7f7f);

        __syncthreads();   // drains prefetch; protects buffers

        if (last) {
            const int tb = cbase + t * TN;
            // append candidates above THRS to the per-row global list
            // 32x32 C/D: col = lane&31, row = (r&3) + 8*(r>>2) + 4*(lane>>5)
            #pragma unroll
            for (int ti = 0; ti < 2; ++ti) {
                const int rb0 = row0 + wm * 64 + ti * 32 + 4 * kb;
                #pragma unroll
                for (int tj = 0; tj < 2; ++tj) {
                    const int cidx = tb + wn * 64 + tj * 32 + l31;
                    #pragma unroll
                    for (int r = 0; r < 16; ++r) {
                        const float v = acc[ti][tj][r];
                        if (v > THRS && cidx < NMEM) {
                            const int rg = rb0 + (r & 3) + 8 * (r >> 2);
                            const int pos = atomicAdd(&cnt[rg], 1);
                            if (pos < CAP)
                                cand_buf[(size_t)rg * CAP + pos] =
                                    make_uint2(__float_as_uint(v * INV_XS),
                                               (unsigned)cidx);
                        }
                        acc[ti][tj][r] = 0.f;              // re-zero for next tile
                    }
                }
            }
        }
        t = tn; kk = kn; p ^= 1;
    }
}

// ---------------------------------------------------------------------------
// Phase C: per row — histogram k-select approx top-64 superset from the
// candidate list -> exact f32 recompute -> exact top-16 -> softmax ->
// scatter -> scale
// ---------------------------------------------------------------------------
__global__ __launch_bounds__(256) void knn_final(
    const int* __restrict__ cnt, const uint2* __restrict__ cand_buf,
    const float* __restrict__ xn, const float* __restrict__ mem,
    const int* __restrict__ labels, float* __restrict__ out)
{
    constexpr float BSCALE = 200.0f;                       // bucket = (v-THR)*200
    __shared__ float cls[NCLS];
    __shared__ uint2 cl[CAP];                              // 4 KB
    __shared__ int   hist[1024];                           // 4 KB
    __shared__ int   psum[256];
    __shared__ float tstar;
    __shared__ int   scount;
    __shared__ int   seli[SELCAP];
    __shared__ float ex[SELCAP];
    __shared__ float fs[TOPK];
    __shared__ int   fi[TOPK];
    __shared__ float zshare;

    const int row = blockIdx.x;
    const int tid = threadIdx.x;
    const int lane = tid & 63, w = tid >> 6;

    // query row quarter for this lane, register-resident (loop-invariant)
    const float4 xr = *(const float4*)(xn + (size_t)row * D + lane * 4);

    for (int c = tid; c < NCLS; c += 256) cls[c] = 0.f;
    for (int i = tid; i < 1024; i += 256) hist[i] = 0;
    int n = cnt[row]; if (n > CAP) n = CAP;
    for (int i = tid; i < n; i += 256) cl[i] = cand_buf[(size_t)row * CAP + i];
    if (tid == 0) scount = 0;
    __syncthreads();

    // histogram of approx sims
    for (int i = tid; i < n; i += 256) {
        const float v = __uint_as_float(cl[i].x);
        int b = (int)((v - THR) * BSCALE);
        b = max(0, min(1023, b));
        atomicAdd(&hist[b], 1);
    }
    __syncthreads();
    psum[tid] = hist[4 * tid] + hist[4 * tid + 1] + hist[4 * tid + 2] + hist[4 * tid + 3];
    __syncthreads();
    if (tid == 0) {
        // threshold t* = lower edge of the bucket where top-count crosses MSEL
        int cum = 0, g = 255;
        for (; g >= 0; --g) {
            if (cum + psum[g] >= MSEL) break;
            cum += psum[g];
        }
        float t = THR;                                     // fallback: all
        if (g >= 0) {
            int bb = 4 * g + 3;
            for (; bb > 4 * g; --bb) {
                cum += hist[bb];
                if (cum >= MSEL) break;
            }
            if (bb == 4 * g) cum += hist[bb];              // ensured >= MSEL
            t = THR + (float)bb * (1.0f / BSCALE);
        }
        tstar = t;
    }
    __syncthreads();
    // collect superset (count in [MSEL, MSEL+few])
    for (int i = tid; i < n; i += 256) {
        const float v = __uint_as_float(cl[i].x);
        if (v >= tstar) {
            const int p = atomicAdd(&scount, 1);
            if (p < SELCAP) seli[p] = (int)cl[i].y;
        }
    }
    __syncthreads();
    int ns = scount; if (ns > SELCAP) ns = SELCAP;

    // exact f32 recompute: wave w handles candidates w, w+4, ...
    for (int c = w; c < ns; c += 4) {
        const float4 mv = *(const float4*)(mem + (size_t)seli[c] * D + lane * 4);
        float s = xr.x * mv.x + xr.y * mv.y + xr.z * mv.z + xr.w * mv.w;
        #pragma unroll
        for (int off = 32; off > 0; off >>= 1) s += __shfl_down(s, off, 64);
        if (lane == 0) ex[c] = s;
    }
    __syncthreads();

    if (tid == 0) {
        // exact top-16 of the <=96 refined candidates
        float kmin = NEG; int kslot = 0;
        #pragma unroll
        for (int s = 0; s < TOPK; ++s) { fs[s] = NEG; fi[s] = -1; }
        for (int c = 0; c < ns; ++c) {
            const float v = ex[c];
            if (v > kmin) {
                fs[kslot] = v; fi[kslot] = seli[c];
                kmin = fs[0]; kslot = 0;
                #pragma unroll
                for (int s = 1; s < TOPK; ++s) {
                    const float tq = fs[s];
                    if (tq < kmin) { kmin = tq; kslot = s; }
                }
            }
        }
        float smax = fs[0];
        #pragma unroll
        for (int s = 1; s < TOPK; ++s) smax = fmaxf(smax, fs[s]);
        float e[TOPK]; float Z = 0.f;
        #pragma unroll
        for (int s = 0; s < TOPK; ++s) {
            e[s] = (fi[s] >= 0) ? expf((fs[s] - smax) * (1.0f / TAU)) : 0.f;
            Z += e[s];
        }
        for (int s = 0; s < TOPK; ++s) {
            if (fi[s] >= 0) cls[labels[fi[s]]] += e[s];    // serial: dup labels safe
        }
        zshare = Z;
    }
    __syncthreads();
    const float scale = LOGIT_SCALE / zshare;
    for (int c = tid; c < NCLS; c += 256)
        out[(size_t)row * NCLS + c] = cls[c] * scale;
}

// ---------------------------------------------------------------------------
extern "C" void kernel_launch(void* const* d_in, const int* in_sizes, int n_in,
                              void* d_out, int out_size, void* d_ws, size_t ws_size,
                              hipStream_t stream) {
    (void)in_sizes; (void)n_in; (void)out_size; (void)ws_size;
    const float* x    = (const float*)d_in[0];
    const float* mean = (const float*)d_in[1];
    const float* stdv = (const float*)d_in[2];
    const float* mem  = (const float*)d_in[3];
    const int*   lbl  = (const int*)d_in[4];
    float* out = (float*)d_out;

    // ws: A1 0.5 MB | XN 2 MB | B1 25.6 MB | cnt 8 KB | cand 8.4 MB
    unsigned char* A1 = (unsigned char*)d_ws;
    float* XN = (float*)(A1 + (size_t)BQ * KTOT);
    unsigned char* B1 = (unsigned char*)(XN + (size_t)BQ * D);
    int* cnt = (int*)(B1 + (size_t)NMEM * KTOT);
    uint2* cand = (uint2*)(cnt + BQ);

    knn_prep<<<BQ, 256, 0, stream>>>(x, mean, stdv, A1, XN, cnt);
    knn_convb<<<(NMEM + 7) / 8, 256, 0, stream>>>(mem, B1);
    knn_gemm_topk<<<NBLK, 256, 0, stream>>>(A1, B1, cnt, cand);
    knn_final<<<BQ, 256, 0, stream>>>(cnt, cand, XN, mem, lbl, out);
}

// Round 6
// 369.835 us; speedup vs baseline: 1.0312x; 1.0312x over previous
//
#include <hip/hip_runtime.h>
#include <math.h>

// Problem constants
constexpr int BQ   = 2048;
constexpr int D    = 256;
constexpr int NMEM = 100000;
constexpr int TOPK = 16;
constexpr int NCLS = 1000;
constexpr float TAU = 0.2f;
constexpr float LOGIT_SCALE = 20.0f;

// fp8(e4m3) GEMM (K=256) for candidate SELECTION only, via 2x-rate
// mfma_scale_f32_32x32x64_f8f6f4 (scales pinned to 1.0 = e8m0 0x7f).
// Round-5 lesson: MFMA is only ~14% of the iteration; the __syncthreads
// vmcnt(0) drain was ~70%. This round: 3-deep LDS buffers + raw s_barrier +
// counted s_waitcnt vmcnt(4) (never 0 in steady state) — loads stay in
// flight ACROSS barriers (T3/T4 pattern). (256,3) removes the round-5
// register spill (WRITE_SIZE 75 MB -> expect ~40).
constexpr int KTOT = 256;        // k-elements (= bytes in fp8)
constexpr int BK   = 64;         // k per k-step (64 B/row, 8 KB tile)
constexpr int TM   = 128;
constexpr int TN   = 128;
constexpr int CTILES = 17;
constexpr int CHUNK  = TN * CTILES;               // 2176
constexpr int NCH    = 48;                        // 48*2176 = 104448 >= 100000
constexpr int RBLK   = BQ / TM;                   // 16
constexpr int NBLK   = RBLK * NCH;                // 768 = 3 blocks/CU exact
constexpr int TOTAL_IT = CTILES * (KTOT / BK);    // 68
constexpr float XSCALE = 16.0f;
constexpr float INV_XS = 0.0625f;
constexpr float THR    = 3.0f;   // candidate floor (mean ~136/row above it)
constexpr float THRS   = 48.0f;  // THR * XSCALE (raw acc scale)
constexpr int CAP    = 512;      // per-row candidate cap
constexpr int MSEL   = 64;       // refinement superset target
constexpr int SELCAP = 96;
constexpr float NEG  = -3.0e38f;

using i32x4  = __attribute__((ext_vector_type(4))) int;
using i32x8  = __attribute__((ext_vector_type(8))) int;
using f32x16 = __attribute__((ext_vector_type(16))) float;

// f32 -> OCP e4m3 (RNE, clamp to 448, flush subnormals — inputs pre-scaled
// so the flush region carries negligible mass).
__device__ __forceinline__ unsigned f2e4m3(float f) {
    const unsigned u = __float_as_uint(f);
    const unsigned s = (u >> 24) & 0x80u;
    const int e = (int)((u >> 23) & 0xff);
    int te = e - 120;                          // e4m3 exponent field (bias 7)
    if (te <= 0) return s;                     // flush tiny
    const unsigned m = u & 0x7fffffu;
    const unsigned r = m + 0x7ffffu + ((m >> 20) & 1u);
    unsigned keep;
    if (r & 0x800000u) { ++te; keep = 0; } else keep = (r >> 20) & 7u;
    if (te >= 16 || (te == 15 && keep == 7)) return s | 0x7eu;  // clamp 448
    return s | ((unsigned)te << 3) | keep;
}

__device__ __forceinline__ void load_lds16(const void* g, void* l) {
    __builtin_amdgcn_global_load_lds((const __attribute__((address_space(1))) void*)g,
                                     (__attribute__((address_space(3))) void*)l,
                                     16, 0, 0);
}

// ---------------------------------------------------------------------------
// Phase A: standardize + L2-normalize; emit A1 = e4m3(16*x_hat), XN = f32
// x_hat, and zero the per-row candidate counters.
// ---------------------------------------------------------------------------
__global__ __launch_bounds__(256) void knn_prep(
    const float* __restrict__ x, const float* __restrict__ mean,
    const float* __restrict__ stdv, unsigned char* __restrict__ A1,
    float* __restrict__ XN, int* __restrict__ cnt)
{
    const int row = blockIdx.x;
    const int t = threadIdx.x;                       // feature index, D==256
    float v = (x[row * D + t] - mean[t]) / stdv[t];
    float s = v * v;
    #pragma unroll
    for (int off = 32; off > 0; off >>= 1) s += __shfl_down(s, off, 64);
    __shared__ float wsum[4];
    __shared__ float nrm;
    const int lane = t & 63, wid = t >> 6;
    if (lane == 0) wsum[wid] = s;
    __syncthreads();
    if (t == 0) {
        nrm = fmaxf(sqrtf(wsum[0] + wsum[1] + wsum[2] + wsum[3]), 1e-6f);
        cnt[row] = 0;
    }
    __syncthreads();
    const float xnv = v / nrm;
    A1[(size_t)row * KTOT + t] = (unsigned char)f2e4m3(xnv * XSCALE);
    XN[(size_t)row * D + t] = xnv;
}

// ---------------------------------------------------------------------------
// Phase A2: mem_features -> B1 = e4m3(mem); 8 rows/block, float4 -> 8 bytes
// ---------------------------------------------------------------------------
__global__ __launch_bounds__(256) void knn_convb(
    const float* __restrict__ mem, unsigned char* __restrict__ B1)
{
    const int tid = threadIdx.x;
    const int rloc = tid >> 5, t = tid & 31;         // 32 threads per row
    const long n = (long)blockIdx.x * 8 + rloc;
    if (n >= NMEM) return;
    const float* src = mem + n * D + t * 8;
    const float4 v0 = *(const float4*)(src);
    const float4 v1 = *(const float4*)(src + 4);
    const float f[8] = {v0.x, v0.y, v0.z, v0.w, v1.x, v1.y, v1.z, v1.w};
    unsigned long long pk = 0;
    #pragma unroll
    for (int i = 0; i < 8; ++i)
        pk |= (unsigned long long)f2e4m3(f[i]) << (8 * i);
    *(unsigned long long*)(B1 + n * KTOT + t * 8) = pk;
}

// ---------------------------------------------------------------------------
// Phase B: 3-deep pipelined MX-fp8 MFMA GEMM (32x32x64, unit scales).
// Per iter t: [ds_read buf t%3] [issue stage(t+2) -> buf (t+2)%3] [MFMA]
//             [epilogue if tile-end] [s_waitcnt vmcnt(4)] [s_barrier].
// Hazards (verified):
//  * WAR: stage(t+2) writes buf (t-1)%3; its readers consumed via lgkmcnt
//    before their iter-(t-1) MFMA, which precedes barrier(t-1->t).
//  * RAW cross-thread: every thread drains stage(t+1) (vmcnt(4): oldest 4
//    of {t+1,t+2}) BEFORE the barrier opening iter t+1.
//  * vmcnt(4) waits on loads issued a full iteration earlier (>2000 cyc >
//    900 cyc HBM latency) -> ~zero stall. Tail iters drop to vmcnt(0).
//  * epilogue atomics inflate the outstanding count -> vmcnt(4) only gets
//    MORE conservative (safe).
//  * (256,3): ~170-reg budget, acc 64 AGPR + ~110 VGPR -> no spill.
// ---------------------------------------------------------------------------
__global__ __launch_bounds__(256, 3) void knn_gemm_topk(
    const unsigned char* __restrict__ A1, const unsigned char* __restrict__ B1,
    int* __restrict__ cnt, uint2* __restrict__ cand_buf)
{
    __shared__ alignas(16) unsigned char As[3][TM * BK];   // 3 x 8 KB
    __shared__ alignas(16) unsigned char Bs[3][TN * BK];   // 3 x 8 KB

    const int tid  = threadIdx.x;
    const int lane = tid & 63, wave = tid >> 6;
    const int wm = wave >> 1, wn = wave & 1;
    const int l31 = lane & 31;                             // out row/col in tile
    const int kb  = lane >> 5;                             // k-half of BK=64

    // chunk-exclusive XCD decode: id%8 == XCD (perf heuristic only)
    const int nblk = blockIdx.x;
    const int xcd = nblk & 7, bi = nblk >> 3;              // bi in [0,96)
    const int rb = bi & 15;                                // rowblk in [0,16)
    const int ch = (bi >> 4) + 6 * xcd;                    // chunk  in [0,48)
    const int row0  = rb * TM;
    const int cbase = ch * CHUNK;

    // frag byte offsets, k-loop invariant: [out-tile][granule c of the 32B]
    // lane reads 32 B = granules (row, 2*kb+c), phys seg = (L-(row>>1))&3
    int aoff[2][2], boff[2][2];
    #pragma unroll
    for (int ti = 0; ti < 2; ++ti) {
        const int ar = wm * 64 + ti * 32 + l31;
        const int br = wn * 64 + ti * 32 + l31;
        #pragma unroll
        for (int c = 0; c < 2; ++c) {
            aoff[ti][c] = ar * BK + (((2 * kb + c) - (ar >> 1)) & 3) * 16;
            boff[ti][c] = br * BK + (((2 * kb + c) - (br >> 1)) & 3) * 16;
        }
    }

    // per-thread staging geometry (16B granule s of this thread)
    const unsigned char* aSrc[2];                          // +kk per stage
    int cSub[2], bSeg[2];
    #pragma unroll
    for (int s = 0; s < 2; ++s) {
        const int ci = s * 256 + tid;
        const int r = ci >> 2, sl = ci & 3;
        aSrc[s] = A1 + (size_t)(row0 + r) * KTOT + (((sl + (r >> 1)) & 3) << 4);
        cSub[s] = r;
        bSeg[s] = ((sl + (r >> 1)) & 3) << 4;
    }
    // per-tile B base pointers (clamped; recomputed only at tile switch)
    const unsigned char* bB[2];
    auto computeBB = [&](int tile) {
        #pragma unroll
        for (int s = 0; s < 2; ++s) {
            int candi = cbase + tile * TN + cSub[s];
            if (candi >= NMEM) candi = NMEM - 1;
            bB[s] = B1 + (size_t)candi * KTOT + bSeg[s];
        }
    };
    auto stage = [&](int buf, int kofs) {                  // 4 loads/thread
        #pragma unroll
        for (int s = 0; s < 2; ++s)
            load_lds16(aSrc[s] + kofs, (char*)As[buf] + s * 4096 + wave * 1024);
        #pragma unroll
        for (int s = 0; s < 2; ++s)
            load_lds16(bB[s] + kofs, (char*)Bs[buf] + s * 4096 + wave * 1024);
    };

    f32x16 acc[2][2];
    #pragma unroll
    for (int i = 0; i < 2; ++i)
        #pragma unroll
        for (int j = 0; j < 2; ++j)
            #pragma unroll
            for (int r = 0; r < 16; ++r) acc[i][j][r] = 0.f;

    // prologue: stages 0 (tile0,k0) and 1 (tile0,k64); wait stage0; barrier
    computeBB(0);
    stage(0, 0);
    stage(1, 64);
    asm volatile("s_waitcnt vmcnt(4)" ::: "memory");
    __builtin_amdgcn_sched_barrier(0);
    __builtin_amdgcn_s_barrier();

    int p = 0;                                             // buf = it % 3
    for (int it = 0; it < TOTAL_IT; ++it) {
        // 1) frag ds_reads from buf p (before stage-issue: avoids the
        //    compiler's conservative vmcnt-before-ds_read)
        const unsigned char* Ab = As[p];
        const unsigned char* Bb = Bs[p];
        i32x8 Afr[2], Bfr[2];
        #pragma unroll
        for (int ti = 0; ti < 2; ++ti) {
            const i32x4 alo = *(const i32x4*)(Ab + aoff[ti][0]);
            const i32x4 ahi = *(const i32x4*)(Ab + aoff[ti][1]);
            Afr[ti] = __builtin_shufflevector(alo, ahi, 0, 1, 2, 3, 4, 5, 6, 7);
            const i32x4 blo = *(const i32x4*)(Bb + boff[ti][0]);
            const i32x4 bhi = *(const i32x4*)(Bb + boff[ti][1]);
            Bfr[ti] = __builtin_shufflevector(blo, bhi, 0, 1, 2, 3, 4, 5, 6, 7);
        }

        // 2) issue stage(it+2) into buf (it+2)%3
        const int is = it + 2;
        const bool have2 = (is < TOTAL_IT);
        if (have2) {
            if ((is & 3) == 0) computeBB(is >> 2);
            int pn = p + 2; if (pn >= 3) pn -= 3;
            stage(pn, (is & 3) << 6);
        }

        // 3) MFMA: 2x2 out-tiles of 32x32, full K=64 per instruction.
        #pragma unroll
        for (int ti = 0; ti < 2; ++ti)
            #pragma unroll
            for (int tj = 0; tj < 2; ++tj)
                acc[ti][tj] = __builtin_amdgcn_mfma_scale_f32_32x32x64_f8f6f4(
                    Afr[ti], Bfr[tj], acc[ti][tj], 0, 0,
                    0, 0x7f7f7f7f, 0, 0x7f7f7f7f);

        // 4) epilogue at tile end (acc + global atomics only; no LDS)
        if ((it & 3) == 3) {
            const int t = it >> 2;
            const int tb = cbase + t * TN;
            // 32x32 C/D: col = lane&31, row = (r&3) + 8*(r>>2) + 4*(lane>>5)
            #pragma unroll
            for (int ti = 0; ti < 2; ++ti) {
                const int rb0 = row0 + wm * 64 + ti * 32 + 4 * kb;
                #pragma unroll
                for (int tj = 0; tj < 2; ++tj) {
                    const int cidx = tb + wn * 64 + tj * 32 + l31;
                    #pragma unroll
                    for (int r = 0; r < 16; ++r) {
                        const float v = acc[ti][tj][r];
                        if (v > THRS && cidx < NMEM) {
                            const int rg = rb0 + (r & 3) + 8 * (r >> 2);
                            const int pos = atomicAdd(&cnt[rg], 1);
                            if (pos < CAP)
                                cand_buf[(size_t)rg * CAP + pos] =
                                    make_uint2(__float_as_uint(v * INV_XS),
                                               (unsigned)cidx);
                        }
                        acc[ti][tj][r] = 0.f;              // re-zero for next tile
                    }
                }
            }
        }

        // 5) counted wait + raw barrier (never drain to 0 in steady state)
        if (it < TOTAL_IT - 1) {
            if (have2) {
                asm volatile("s_waitcnt vmcnt(4)" ::: "memory");
            } else {
                asm volatile("s_waitcnt vmcnt(0)" ::: "memory");
            }
            __builtin_amdgcn_sched_barrier(0);
            __builtin_amdgcn_s_barrier();
        }
        ++p; if (p >= 3) p = 0;
    }
}

// ---------------------------------------------------------------------------
// Phase C: per row — histogram k-select approx top-64 superset from the
// candidate list -> exact f32 recompute -> exact top-16 -> softmax ->
// scatter -> scale
// ---------------------------------------------------------------------------
__global__ __launch_bounds__(256) void knn_final(
    const int* __restrict__ cnt, const uint2* __restrict__ cand_buf,
    const float* __restrict__ xn, const float* __restrict__ mem,
    const int* __restrict__ labels, float* __restrict__ out)
{
    constexpr float BSCALE = 200.0f;                       // bucket = (v-THR)*200
    __shared__ float cls[NCLS];
    __shared__ uint2 cl[CAP];                              // 4 KB
    __shared__ int   hist[1024];                           // 4 KB
    __shared__ int   psum[256];
    __shared__ float tstar;
    __shared__ int   scount;
    __shared__ int   seli[SELCAP];
    __shared__ float ex[SELCAP];
    __shared__ float fs[TOPK];
    __shared__ int   fi[TOPK];
    __shared__ float zshare;

    const int row = blockIdx.x;
    const int tid = threadIdx.x;
    const int lane = tid & 63, w = tid >> 6;

    // query row quarter for this lane, register-resident (loop-invariant)
    const float4 xr = *(const float4*)(xn + (size_t)row * D + lane * 4);

    for (int c = tid; c < NCLS; c += 256) cls[c] = 0.f;
    for (int i = tid; i < 1024; i += 256) hist[i] = 0;
    int n = cnt[row]; if (n > CAP) n = CAP;
    for (int i = tid; i < n; i += 256) cl[i] = cand_buf[(size_t)row * CAP + i];
    if (tid == 0) scount = 0;
    __syncthreads();

    // histogram of approx sims
    for (int i = tid; i < n; i += 256) {
        const float v = __uint_as_float(cl[i].x);
        int b = (int)((v - THR) * BSCALE);
        b = max(0, min(1023, b));
        atomicAdd(&hist[b], 1);
    }
    __syncthreads();
    psum[tid] = hist[4 * tid] + hist[4 * tid + 1] + hist[4 * tid + 2] + hist[4 * tid + 3];
    __syncthreads();
    if (tid == 0) {
        // threshold t* = lower edge of the bucket where top-count crosses MSEL
        int cum = 0, g = 255;
        for (; g >= 0; --g) {
            if (cum + psum[g] >= MSEL) break;
            cum += psum[g];
        }
        float t = THR;                                     // fallback: all
        if (g >= 0) {
            int bb = 4 * g + 3;
            for (; bb > 4 * g; --bb) {
                cum += hist[bb];
                if (cum >= MSEL) break;
            }
            if (bb == 4 * g) cum += hist[bb];              // ensured >= MSEL
            t = THR + (float)bb * (1.0f / BSCALE);
        }
        tstar = t;
    }
    __syncthreads();
    // collect superset (count in [MSEL, MSEL+few])
    for (int i = tid; i < n; i += 256) {
        const float v = __uint_as_float(cl[i].x);
        if (v >= tstar) {
            const int p = atomicAdd(&scount, 1);
            if (p < SELCAP) seli[p] = (int)cl[i].y;
        }
    }
    __syncthreads();
    int ns = scount; if (ns > SELCAP) ns = SELCAP;

    // exact f32 recompute: wave w handles candidates w, w+4, ...
    for (int c = w; c < ns; c += 4) {
        const float4 mv = *(const float4*)(mem + (size_t)seli[c] * D + lane * 4);
        float s = xr.x * mv.x + xr.y * mv.y + xr.z * mv.z + xr.w * mv.w;
        #pragma unroll
        for (int off = 32; off > 0; off >>= 1) s += __shfl_down(s, off, 64);
        if (lane == 0) ex[c] = s;
    }
    __syncthreads();

    if (tid == 0) {
        // exact top-16 of the <=96 refined candidates
        float kmin = NEG; int kslot = 0;
        #pragma unroll
        for (int s = 0; s < TOPK; ++s) { fs[s] = NEG; fi[s] = -1; }
        for (int c = 0; c < ns; ++c) {
            const float v = ex[c];
            if (v > kmin) {
                fs[kslot] = v; fi[kslot] = seli[c];
                kmin = fs[0]; kslot = 0;
                #pragma unroll
                for (int s = 1; s < TOPK; ++s) {
                    const float tq = fs[s];
                    if (tq < kmin) { kmin = tq; kslot = s; }
                }
            }
        }
        float smax = fs[0];
        #pragma unroll
        for (int s = 1; s < TOPK; ++s) smax = fmaxf(smax, fs[s]);
        float e[TOPK]; float Z = 0.f;
        #pragma unroll
        for (int s = 0; s < TOPK; ++s) {
            e[s] = (fi[s] >= 0) ? expf((fs[s] - smax) * (1.0f / TAU)) : 0.f;
            Z += e[s];
        }
        for (int s = 0; s < TOPK; ++s) {
            if (fi[s] >= 0) cls[labels[fi[s]]] += e[s];    // serial: dup labels safe
        }
        zshare = Z;
    }
    __syncthreads();
    const float scale = LOGIT_SCALE / zshare;
    for (int c = tid; c < NCLS; c += 256)
        out[(size_t)row * NCLS + c] = cls[c] * scale;
}

// ---------------------------------------------------------------------------
extern "C" void kernel_launch(void* const* d_in, const int* in_sizes, int n_in,
                              void* d_out, int out_size, void* d_ws, size_t ws_size,
                              hipStream_t stream) {
    (void)in_sizes; (void)n_in; (void)out_size; (void)ws_size;
    const float* x    = (const float*)d_in[0];
    const float* mean = (const float*)d_in[1];
    const float* stdv = (const float*)d_in[2];
    const float* mem  = (const float*)d_in[3];
    const int*   lbl  = (const int*)d_in[4];
    float* out = (float*)d_out;

    // ws: A1 0.5 MB | XN 2 MB | B1 25.6 MB | cnt 8 KB | cand 8.4 MB
    unsigned char* A1 = (unsigned char*)d_ws;
    float* XN = (float*)(A1 + (size_t)BQ * KTOT);
    unsigned char* B1 = (unsigned char*)(XN + (size_t)BQ * D);
    int* cnt = (int*)(B1 + (size_t)NMEM * KTOT);
    uint2* cand = (uint2*)(cnt + BQ);

    knn_prep<<<BQ, 256, 0, stream>>>(x, mean, stdv, A1, XN, cnt);
    knn_convb<<<(NMEM + 7) / 8, 256, 0, stream>>>(mem, B1);
    knn_gemm_topk<<<NBLK, 256, 0, stream>>>(A1, B1, cnt, cand);
    knn_final<<<BQ, 256, 0, stream>>>(cnt, cand, XN, mem, lbl, out);
}